// Round 16
// baseline (3576.802 us; speedup 1.0000x reference)
//
#include <hip/hip_runtime.h>

#define Hh 64
#define Tt 2048
#define Bb 256
#define NL 3

typedef _Float16 h2 __attribute__((ext_vector_type(2)));

__device__ __forceinline__ h2 uh2(unsigned u){ union{unsigned u; h2 h;}d; d.u=u; return d.h; }
__device__ __forceinline__ unsigned h2u(h2 h){ union{h2 h; unsigned u;}d; d.h=h; return d.u; }
#define FDOT2(a,b,c) __builtin_amdgcn_fdot2((a),(b),(c),false)

__device__ __forceinline__ float fast_sigmoid(float x){ return 1.0f/(1.0f+__expf(-x)); }
__device__ __forceinline__ float fast_tanh(float x){ float e=__expf(2.0f*x); return 1.0f-2.0f/(e+1.0f); }

#define REPEAT16(M) M(0) M(1) M(2) M(3) M(4) M(5) M(6) M(7) \
                    M(8) M(9) M(10) M(11) M(12) M(13) M(14) M(15)

__global__ void conv_w(const float* __restrict__ src, _Float16* __restrict__ dst, int n){
    int i = blockIdx.x*256 + threadIdx.x;
    if (i < n) dst[i] = (_Float16)src[i];
}

__global__ __launch_bounds__(256)
void prep_x(const float* __restrict__ x, _Float16* __restrict__ xh){
    __shared__ float tile[64][65];
    const int b = blockIdx.x, tc = blockIdx.y;
    const int tt = threadIdx.x & 63, hq = threadIdx.x >> 6;
    const long xb = (long)b * Hh * Tt;
#pragma unroll
    for (int k=0;k<16;++k){ int h = hq*16+k; tile[h][tt] = x[xb + (long)h*Tt + tc*64 + tt]; }
    __syncthreads();
    _Float16* dst = xh + ((long)b*Tt + tc*64 + tt)*Hh + hq*16;
#pragma unroll
    for (int k=0;k<16;++k) dst[k] = (_Float16)tile[hq*16+k][tt];
}

// ---- main: 12 waves/block, 4 per layer, layers pipelined with skew 1 ----
// Wave (l, s, uh); lane (kh, jj). Each lane: 3 half-rows of packed f16 = 48 dw.
//
// R3-R15 verdict: the allocator will NOT carry ~50 loop-invariant loaded
// values across this barriered loop -- every pin (launch_bounds, waves_per_eu,
// LDS pad, tied asm, early-clobber mov, volatile loads, AGPR parking) ended in
// per-phase spill-reload or remat, re-streaming 147KB/block/phase from L2 at
// ~78 B/cyc = the entire runtime. So stop: make the per-phase re-read EXPLICIT
// and put it on the fat local pipe. All 3 layers' f16 weights (147,456 B) live
// in LDS (+10,240 B buffers = 157,696 <= 160K), staged once. Per-lane-private
// layout (48 dwords contiguous at tid*192B): stride 192 spreads 64 lanes
// uniformly 4-per-bank-quad -> even b128 access. LDS pipe ~112-128 B/cyc vs
// L2's ~78, and no allocator involvement. In-loop opaque pointer (asm "+v")
// prevents LICM from hoisting the ds_reads and re-creating the spill.
__global__
__attribute__((amdgpu_flat_work_group_size(768, 768)))
void gru_pipe(const _Float16* __restrict__ xh, float* __restrict__ out,
              const _Float16* __restrict__ wih16, const _Float16* __restrict__ whh16,
              const float* __restrict__ bih, const float* __restrict__ bhh)
{
    const int b   = blockIdx.x;
    const int tid = threadIdx.x;
    const int w   = tid >> 6;        // 0..11
    const int l   = w >> 2;          // layer 0..2
    const int s   = (w >> 1) & 1;    // role
    const int uh  = w & 1;           // unit half
    const int ln  = tid & 63;
    const int kh  = ln >> 5;         // k half
    const int jj  = ln & 31;
    const int j   = uh * 32 + jj;    // hidden unit

    const int gA = s ? 64 + j : j;
    const h2* pa = (const h2*)wih16 + ((long)l * 192 + gA) * 32 + kh * 16;
    const h2* pb = (const h2*)whh16 + ((long)l * 192 + gA) * 32 + kh * 16;
    const h2* pc = (const h2*)(s ? wih16 : whh16) + ((long)l * 192 + 128 + j) * 32 + kh * 16;

    __shared__ __align__(16) unsigned wlds[768 * 48];  // 147,456 B: all weights
    __shared__ __align__(16) _Float16 hbuf[NL][2][Hh]; // per-layer h, dbuf by parity
    __shared__ __align__(16) _Float16 xbuf[2][Hh];     // layer-0 input, dbuf
    __shared__ float ubuf[NL][Hh];                     // r*(Whh_n.h + bhn), fp32
    __shared__ float obuf[2][32][33];                  // layer-2 out staging, +1 pad

    // One-time stage: each lane parks its own 48 dwords at tid*192B.
    {
        unsigned* myw = &wlds[tid * 48];
#pragma unroll
        for (int k = 0; k < 16; ++k) {
            myw[k]      = h2u(pa[k]);
            myw[16 + k] = h2u(pb[k]);
            myw[32 + k] = h2u(pc[k]);
        }
    }

    float bA = 0.0f, bC = 0.0f;
    if (kh == 0) {
        bA = bih[l*192 + gA] + bhh[l*192 + gA];
        bC = s ? bih[l*192 + 128 + j] : bhh[l*192 + 128 + j];
    }

    const long ib  = (long)b * Hh * Tt;   // [B,H,T] out base
    const long ibh = (long)b * Tt * Hh;   // [B,T,H] xh base

    if (tid < NL * 2 * Hh) ((_Float16*)hbuf)[tid] = (_Float16)0.0f;
    float hprev = 0.0f;
    _Float16 xcur = (_Float16)0.0f, xnext = (_Float16)0.0f;  // wave 8 duty
    if (w == 8) {
        xbuf[0][ln] = xh[ibh + 0 * Hh + ln];
        xcur        = xh[ibh + 1 * Hh + ln];
    }
    __syncthreads();

    const uint4* xsA = (const uint4*)((l == 0) ? xbuf[0] : hbuf[l - 1][0]) + kh * 4;
    const uint4* xsB = (const uint4*)((l == 0) ? xbuf[1] : hbuf[l - 1][1]) + kh * 4;
    const uint4* hsA = (const uint4*)hbuf[l][0] + kh * 4;
    const uint4* hsB = (const uint4*)hbuf[l][1] + kh * 4;

    for (int p = 0; p < Tt + NL - 1; ++p) {
        const int rd = p & 1;
        const int t  = p - l;
        const bool act = (t >= 0) && (t < Tt);

        // Iteration-scoped opaque weight offset: ds_reads can't be hoisted.
        unsigned woff = tid * 192u;
        asm volatile("" : "+v"(woff));
        const uint4* wq = (const uint4*)((const char*)wlds + woff);

        if (w == 8 && p + 2 < Tt) xnext = xh[ibh + (long)(p + 2) * Hh + ln];

        float accA = bA, accB = 0.0f, accC = bC;
        float zg = 0.0f;
        if (act) {
            const uint4* xs4 = rd ? xsB : xsA;
            const uint4* hs4 = rd ? hsB : hsA;
#define QSTEP(q, S3)  { \
    const uint4 X = xs4[q]; const uint4 Hv = hs4[q]; \
    const uint4 wA = wq[q], wB = wq[4+q], wC = wq[8+q]; \
    accA = FDOT2(uh2(wA.x), uh2(X.x), accA); accB = FDOT2(uh2(wB.x), uh2(Hv.x), accB); accC = FDOT2(uh2(wC.x), uh2(S3.x), accC); \
    accA = FDOT2(uh2(wA.y), uh2(X.y), accA); accB = FDOT2(uh2(wB.y), uh2(Hv.y), accB); accC = FDOT2(uh2(wC.y), uh2(S3.y), accC); \
    accA = FDOT2(uh2(wA.z), uh2(X.z), accA); accB = FDOT2(uh2(wB.z), uh2(Hv.z), accB); accC = FDOT2(uh2(wC.z), uh2(S3.z), accC); \
    accA = FDOT2(uh2(wA.w), uh2(X.w), accA); accB = FDOT2(uh2(wB.w), uh2(Hv.w), accB); accC = FDOT2(uh2(wC.w), uh2(S3.w), accC); }
            if (s == 0) {
                QSTEP(0, Hv)
                QSTEP(1, Hv)
                QSTEP(2, Hv)
                QSTEP(3, Hv)
            } else {
                QSTEP(0, X)
                QSTEP(1, X)
                QSTEP(2, X)
                QSTEP(3, X)
            }
#undef QSTEP
            accA += __shfl_xor(accA, 32);
            accB += __shfl_xor(accB, 32);
            accC += __shfl_xor(accC, 32);
            const float g = fast_sigmoid(accA + accB);   // r (s=0) or z (s=1)
            if (s == 0) {
                if (kh == 0) ubuf[l][j] = g * accC;      // u = r*(Whh_n.h + bhn)
            }
            zg = g;
        }
        __syncthreads();   // B1: u visible

        if (act && s == 1) {
            const float n = fast_tanh(accC + ubuf[l][j]);   // accC = Wih_n.x + bxn
            const float hnew = fmaf(zg, hprev - n, n);      // (1-z)*n + z*h
            hprev = hnew;
            if (kh == 0) {
                hbuf[l][rd ^ 1][j] = (_Float16)hnew;
                if (l == NL - 1) obuf[uh][jj][t & 31] = hnew;
            }
        }
        if (w == 8) {
            if (p + 1 < Tt) xbuf[rd ^ 1][ln] = xcur;
            xcur = xnext;
        }
        __syncthreads();   // B2: h/x published for next phase

        if ((w >> 1) == 5 && act && (t & 31) == 31) {
            const float* srow = obuf[uh][jj] + kh * 16;
            float4* dst = (float4*)(out + ib + (long)j * Tt + (t - 31) + kh * 16);
            dst[0] = make_float4(srow[0],  srow[1],  srow[2],  srow[3]);
            dst[1] = make_float4(srow[4],  srow[5],  srow[6],  srow[7]);
            dst[2] = make_float4(srow[8],  srow[9],  srow[10], srow[11]);
            dst[3] = make_float4(srow[12], srow[13], srow[14], srow[15]);
        }
    }
}

extern "C" void kernel_launch(void* const* d_in, const int* in_sizes, int n_in,
                              void* d_out, int out_size, void* d_ws, size_t ws_size,
                              hipStream_t stream) {
    const float* x   = (const float*)d_in[0];   // [B, H, T]
    const float* Wih = (const float*)d_in[1];   // [3, 192, 64]
    const float* Whh = (const float*)d_in[2];   // [3, 192, 64]
    const float* bih = (const float*)d_in[3];   // [3, 192]
    const float* bhh = (const float*)d_in[4];   // [3, 192]
    float* out = (float*)d_out;                 // [B, H, T]

    _Float16* xh    = (_Float16*)d_ws;
    _Float16* wih16 = (_Float16*)((char*)d_ws + 67108864);
    _Float16* whh16 = (_Float16*)((char*)d_ws + 67108864 + 73728);
    const int nW = NL * 192 * 64;  // 36864

    conv_w<<<(nW + 255) / 256, 256, 0, stream>>>(Wih, wih16, nW);
    conv_w<<<(nW + 255) / 256, 256, 0, stream>>>(Whh, whh16, nW);
    prep_x<<<dim3(Bb, Tt / 64), 256, 0, stream>>>(x, xh);
    gru_pipe<<<Bb, 768, 0, stream>>>(xh, out, wih16, whh16, bih, bhh);
}

// Round 17
// 2207.556 us; speedup vs baseline: 1.6203x; 1.6203x over previous
//
#include <hip/hip_runtime.h>

#define Hh 64
#define Tt 2048
#define Bb 256
#define NL 3

typedef _Float16 h2 __attribute__((ext_vector_type(2)));

__device__ __forceinline__ h2 uh2(unsigned u){ union{unsigned u; h2 h;}d; d.u=u; return d.h; }
__device__ __forceinline__ unsigned h2u(h2 h){ union{h2 h; unsigned u;}d; d.h=h; return d.u; }
#define FDOT2(a,b,c) __builtin_amdgcn_fdot2((a),(b),(c),false)

__device__ __forceinline__ float fast_sigmoid(float x){ return 1.0f/(1.0f+__expf(-x)); }
__device__ __forceinline__ float fast_tanh(float x){ float e=__expf(2.0f*x); return 1.0f-2.0f/(e+1.0f); }

#define REPEAT16(M) M(0) M(1) M(2) M(3) M(4) M(5) M(6) M(7) \
                    M(8) M(9) M(10) M(11) M(12) M(13) M(14) M(15)

__global__ void conv_w(const float* __restrict__ src, _Float16* __restrict__ dst, int n){
    int i = blockIdx.x*256 + threadIdx.x;
    if (i < n) dst[i] = (_Float16)src[i];
}

__global__ __launch_bounds__(256)
void prep_x(const float* __restrict__ x, _Float16* __restrict__ xh){
    __shared__ float tile[64][65];
    const int b = blockIdx.x, tc = blockIdx.y;
    const int tt = threadIdx.x & 63, hq = threadIdx.x >> 6;
    const long xb = (long)b * Hh * Tt;
#pragma unroll
    for (int k=0;k<16;++k){ int h = hq*16+k; tile[h][tt] = x[xb + (long)h*Tt + tc*64 + tt]; }
    __syncthreads();
    _Float16* dst = xh + ((long)b*Tt + tc*64 + tt)*Hh + hq*16;
#pragma unroll
    for (int k=0;k<16;++k) dst[k] = (_Float16)tile[hq*16+k][tt];
}

// ---- main: 12 waves/block, 4 per layer, layers pipelined with skew 1 ----
// Wave (l, s, uh); lane (kh, jj). Per lane 48 weight dwords/phase, re-read
// every phase (R3-R15: the compiler refuses register residency for loaded
// invariants -- the re-read is physics now; route it on TWO pipes):
//   A operand (x-side, 16 dw): compiler-streamed from L2  (~56 B/cyc/CU,
//     measured ceiling, R11/R12 = pure L2-bound at 2564 cyc/phase)
//   B,C operands (32 dw): LDS, CONFLICT-FREE layout wlds4[q*768+tid] --
//     consecutive lanes read consecutive 16B = the m134 85 B/cyc pattern.
//     (R16's lane-private rows, stride 48 dw === 16 mod 32 banks, were a
//      32-way conflict: 9.07e8 conflict cycles. Layout is everything.)
// Overlapped: phase ~= max(98KB/85, 49KB/56, VALU) ~= 1250 cyc vs 2564.
__global__
__attribute__((amdgpu_flat_work_group_size(768, 768)))
void gru_pipe(const _Float16* __restrict__ xh, float* __restrict__ out,
              const _Float16* __restrict__ wih16, const _Float16* __restrict__ whh16,
              const float* __restrict__ bih, const float* __restrict__ bhh)
{
    const int b   = blockIdx.x;
    const int tid = threadIdx.x;
    const int w   = tid >> 6;        // 0..11
    const int l   = w >> 2;          // layer 0..2
    const int s   = (w >> 1) & 1;    // role
    const int uh  = w & 1;           // unit half
    const int ln  = tid & 63;
    const int kh  = ln >> 5;         // k half
    const int jj  = ln & 31;
    const int j   = uh * 32 + jj;    // hidden unit

    const int gA = s ? 64 + j : j;
    const h2* pa = (const h2*)wih16 + ((long)l * 192 + gA) * 32 + kh * 16;
    const h2* pb = (const h2*)whh16 + ((long)l * 192 + gA) * 32 + kh * 16;
    const h2* pc = (const h2*)(s ? wih16 : whh16) + ((long)l * 192 + 128 + j) * 32 + kh * 16;

    // A operand: named regs; the compiler sinks these to per-phase L2 loads
    // (observed R4-R14) -- that IS the intended global stream.
#define LW(k) h2 A##k = pa[k];
    REPEAT16(LW)
#undef LW

    __shared__ __align__(16) uint4 wlds4[8 * 768];     // 98,304 B: B,C operands
    __shared__ __align__(16) _Float16 hbuf[NL][2][Hh]; // per-layer h, dbuf by parity
    __shared__ __align__(16) _Float16 xbuf[2][Hh];     // layer-0 input, dbuf
    __shared__ float ubuf[NL][Hh];                     // r*(Whh_n.h + bhn), fp32
    __shared__ float obuf[2][32][33];                  // layer-2 out staging, +1 pad

    // Stage B,C: slot q of lane tid at wlds4[q*768 + tid] -> reads AND writes
    // are consecutive-lane/consecutive-16B: conflict-free.
    {
        const uint4* pb4 = (const uint4*)pb;
        const uint4* pc4 = (const uint4*)pc;
#pragma unroll
        for (int q = 0; q < 4; ++q) {
            wlds4[q * 768 + tid]       = pb4[q];
            wlds4[(4 + q) * 768 + tid] = pc4[q];
        }
    }

    float bA = 0.0f, bC = 0.0f;
    if (kh == 0) {
        bA = bih[l*192 + gA] + bhh[l*192 + gA];
        bC = s ? bih[l*192 + 128 + j] : bhh[l*192 + 128 + j];
    }

    const long ib  = (long)b * Hh * Tt;   // [B,H,T] out base
    const long ibh = (long)b * Tt * Hh;   // [B,T,H] xh base

    if (tid < NL * 2 * Hh) ((_Float16*)hbuf)[tid] = (_Float16)0.0f;
    float hprev = 0.0f;
    _Float16 xcur = (_Float16)0.0f, xnext = (_Float16)0.0f;  // wave 8 duty
    if (w == 8) {
        xbuf[0][ln] = xh[ibh + 0 * Hh + ln];
        xcur        = xh[ibh + 1 * Hh + ln];
    }
    __syncthreads();

    const uint4* xsA = (const uint4*)((l == 0) ? xbuf[0] : hbuf[l - 1][0]) + kh * 4;
    const uint4* xsB = (const uint4*)((l == 0) ? xbuf[1] : hbuf[l - 1][1]) + kh * 4;
    const uint4* hsA = (const uint4*)hbuf[l][0] + kh * 4;
    const uint4* hsB = (const uint4*)hbuf[l][1] + kh * 4;

    for (int p = 0; p < Tt + NL - 1; ++p) {
        const int rd = p & 1;
        const int t  = p - l;
        const bool act = (t >= 0) && (t < Tt);

        // Iteration-scoped opaque LDS offset: ds_reads stay in-loop (R16 ✓),
        // so no pre-loop hoist -> no register-pressure/spill relapse.
        unsigned woff = tid * 16u;
        asm volatile("" : "+v"(woff));
        const char* wp = (const char*)wlds4 + woff;

        if (w == 8 && p + 2 < Tt) xnext = xh[ibh + (long)(p + 2) * Hh + ln];

        float accA = bA, accB = 0.0f, accC = bC;
        float zg = 0.0f;
        if (act) {
            const uint4* xs4 = rd ? xsB : xsA;
            const uint4* hs4 = rd ? hsB : hsA;
#define QSTEP(q, k0, k1, k2, k3, S3)  { \
    const uint4 X = xs4[q]; const uint4 Hv = hs4[q]; \
    const uint4 wB = *(const uint4*)(wp + (q) * 12288); \
    const uint4 wC = *(const uint4*)(wp + (4 + q) * 12288); \
    accA = FDOT2(A##k0, uh2(X.x), accA); accB = FDOT2(uh2(wB.x), uh2(Hv.x), accB); accC = FDOT2(uh2(wC.x), uh2(S3.x), accC); \
    accA = FDOT2(A##k1, uh2(X.y), accA); accB = FDOT2(uh2(wB.y), uh2(Hv.y), accB); accC = FDOT2(uh2(wC.y), uh2(S3.y), accC); \
    accA = FDOT2(A##k2, uh2(X.z), accA); accB = FDOT2(uh2(wB.z), uh2(Hv.z), accB); accC = FDOT2(uh2(wC.z), uh2(S3.z), accC); \
    accA = FDOT2(A##k3, uh2(X.w), accA); accB = FDOT2(uh2(wB.w), uh2(Hv.w), accB); accC = FDOT2(uh2(wC.w), uh2(S3.w), accC); }
            if (s == 0) {
                QSTEP(0,  0,  1,  2,  3, Hv)
                QSTEP(1,  4,  5,  6,  7, Hv)
                QSTEP(2,  8,  9, 10, 11, Hv)
                QSTEP(3, 12, 13, 14, 15, Hv)
            } else {
                QSTEP(0,  0,  1,  2,  3, X)
                QSTEP(1,  4,  5,  6,  7, X)
                QSTEP(2,  8,  9, 10, 11, X)
                QSTEP(3, 12, 13, 14, 15, X)
            }
#undef QSTEP
            accA += __shfl_xor(accA, 32);
            accB += __shfl_xor(accB, 32);
            accC += __shfl_xor(accC, 32);
            const float g = fast_sigmoid(accA + accB);   // r (s=0) or z (s=1)
            if (s == 0) {
                if (kh == 0) ubuf[l][j] = g * accC;      // u = r*(Whh_n.h + bhn)
            }
            zg = g;
        }
        __syncthreads();   // B1: u visible

        if (act && s == 1) {
            const float n = fast_tanh(accC + ubuf[l][j]);   // accC = Wih_n.x + bxn
            const float hnew = fmaf(zg, hprev - n, n);      // (1-z)*n + z*h
            hprev = hnew;
            if (kh == 0) {
                hbuf[l][rd ^ 1][j] = (_Float16)hnew;
                if (l == NL - 1) obuf[uh][jj][t & 31] = hnew;
            }
        }
        if (w == 8) {
            if (p + 1 < Tt) xbuf[rd ^ 1][ln] = xcur;
            xcur = xnext;
        }
        __syncthreads();   // B2: h/x published for next phase

        if ((w >> 1) == 5 && act && (t & 31) == 31) {
            const float* srow = obuf[uh][jj] + kh * 16;
            float4* dst = (float4*)(out + ib + (long)j * Tt + (t - 31) + kh * 16);
            dst[0] = make_float4(srow[0],  srow[1],  srow[2],  srow[3]);
            dst[1] = make_float4(srow[4],  srow[5],  srow[6],  srow[7]);
            dst[2] = make_float4(srow[8],  srow[9],  srow[10], srow[11]);
            dst[3] = make_float4(srow[12], srow[13], srow[14], srow[15]);
        }
    }
}

extern "C" void kernel_launch(void* const* d_in, const int* in_sizes, int n_in,
                              void* d_out, int out_size, void* d_ws, size_t ws_size,
                              hipStream_t stream) {
    const float* x   = (const float*)d_in[0];   // [B, H, T]
    const float* Wih = (const float*)d_in[1];   // [3, 192, 64]
    const float* Whh = (const float*)d_in[2];   // [3, 192, 64]
    const float* bih = (const float*)d_in[3];   // [3, 192]
    const float* bhh = (const float*)d_in[4];   // [3, 192]
    float* out = (float*)d_out;                 // [B, H, T]

    _Float16* xh    = (_Float16*)d_ws;
    _Float16* wih16 = (_Float16*)((char*)d_ws + 67108864);
    _Float16* whh16 = (_Float16*)((char*)d_ws + 67108864 + 73728);
    const int nW = NL * 192 * 64;  // 36864

    conv_w<<<(nW + 255) / 256, 256, 0, stream>>>(Wih, wih16, nW);
    conv_w<<<(nW + 255) / 256, 256, 0, stream>>>(Whh, whh16, nW);
    prep_x<<<dim3(Bb, Tt / 64), 256, 0, stream>>>(x, xh);
    gru_pipe<<<Bb, 768, 0, stream>>>(xh, out, wih16, whh16, bih, bhh);
}